// Round 6
// baseline (98.953 us; speedup 1.0000x reference)
//
#include <hip/hip_runtime.h>
#include <math.h>

#define N_PTS 1024
#define D 128
#define QL 400
#define PLD 1200            // 3*QL
#define SQRT_D_INV 0.08838834764831845f
#define NB 256              // grid blocks (co-residency proof: 2 blocks/CU capacity)

typedef __attribute__((ext_vector_type(8))) short bf16x8;
typedef __attribute__((ext_vector_type(4))) float f32x4;
typedef unsigned short u16;

#define GLOBAL_AS __attribute__((address_space(1)))
#define LDS_AS    __attribute__((address_space(3)))

__device__ __forceinline__ u16 f2bf(float x) {
    union { float f; unsigned u; } v; v.f = x;
    unsigned r = v.u + 0x7fff + ((v.u >> 16) & 1);   // RNE
    return (u16)(r >> 16);
}
__device__ __forceinline__ float b2f(u16 h) {
    union { unsigned u; float f; } v; v.u = ((unsigned)h) << 16;
    return v.f;
}

// Monotonic grid barrier: all NB blocks arrive; target = epoch*NB.
// cnt is memset to 0 by kernel_launch each call -> deterministic.
__device__ __forceinline__ void grid_bar(unsigned* cnt, int epoch) {
    __syncthreads();
    if (threadIdx.x == 0) {
        __threadfence();   // agent-scope release: L2 writeback (cross-XCD vis)
        __hip_atomic_fetch_add(cnt, 1u, __ATOMIC_RELAXED, __HIP_MEMORY_SCOPE_AGENT);
        const unsigned target = (unsigned)epoch * NB;
        int guard = 0;
        while (__hip_atomic_load(cnt, __ATOMIC_RELAXED, __HIP_MEMORY_SCOPE_AGENT) < target) {
            __builtin_amdgcn_s_sleep(2);
            if (++guard > (1 << 24)) break;   // fail-safe: never expected
        }
        __threadfence();   // agent-scope acquire: invalidate stale L1/L2
    }
    __syncthreads();
}

// ------------------------------------------------------------------
// ONE kernel, 4 phases:
//  P0: qkv = features@W+b -> qb(1/sqrt(D))/kb/vT (blocks 0..95)
//      Tcat convert (blocks 96..245)
//  P1: Pb = (kb @ Tcat^T)*1/sqrt(D), 304 tiles grid-strided
//  P2: flash: 512 (i-tile,chunk) units, 2 per block sharing P-slab
//  P3: reduce partials + normalize -> out
// ------------------------------------------------------------------
__global__ __launch_bounds__(256, 2) void mega_kernel(
    const float* __restrict__ features, const float* __restrict__ W,
    const float* __restrict__ bias,
    const float* __restrict__ tx, const float* __restrict__ ty,
    const float* __restrict__ tz,
    const float* __restrict__ vd,
    u16* __restrict__ qb, u16* __restrict__ kb, u16* __restrict__ vT,
    u16* __restrict__ Tcat, u16* __restrict__ Pb,
    float* __restrict__ part, float* __restrict__ rowsumP,
    float* __restrict__ out, unsigned* __restrict__ barcnt)
{
    __shared__ __align__(16) char smem_raw[43520];
    u16* As = (u16*)smem_raw;            // 8192 u16 (16 KB)
    u16* Bs = As + 8192;                 // 8192 u16 (16 KB)
    u16* Pl = (u16*)smem_raw;            // 19456 u16 (38 KB)
    u16* Ps = (u16*)(smem_raw + 38912);  // 2048 u16 (4 KB)
    float* rsw = (float*)(smem_raw + 43008);   // 4x16 f32

    const int tid = threadIdx.x;
    const int bx = blockIdx.x;
    const int wave = tid >> 6, lane = tid & 63;
    const int wr = wave >> 1, wc = wave & 1;
    const int l15 = lane & 15, l4 = lane >> 4;

    // ================= P0 =================
    if (bx < 96) {
        const int bm = (bx / 6) * 64;
        const int bn = (bx % 6) * 64;
        #pragma unroll
        for (int r0 = 0; r0 < 4; ++r0) {
            int unit = r0 * 256 + tid;
            int row = unit >> 4, c16 = unit & 15;
            const float* ga = features + (size_t)(bm + row) * D + c16 * 8;
            float4 a0 = *(const float4*)ga;
            float4 a1 = *(const float4*)(ga + 4);
            u16 h[8] = {f2bf(a0.x), f2bf(a0.y), f2bf(a0.z), f2bf(a0.w),
                        f2bf(a1.x), f2bf(a1.y), f2bf(a1.z), f2bf(a1.w)};
            *(bf16x8*)(As + row * 128 + ((c16 ^ (row & 7)) * 8)) = *(bf16x8*)h;
        }
        #pragma unroll
        for (int r2 = 0; r2 < 8; ++r2) {
            int k = r2 * 16 + (tid >> 4);
            int nl = (tid & 15) * 4;
            float4 w4 = *(const float4*)&W[(size_t)k * 384 + bn + nl];
            float wv[4] = {w4.x, w4.y, w4.z, w4.w};
            #pragma unroll
            for (int e = 0; e < 4; ++e) {
                int n = nl + e;
                Bs[n * 128 + (((k >> 3) ^ (n & 7)) << 3) + (k & 7)] = f2bf(wv[e]);
            }
        }
        __syncthreads();

        f32x4 acc[2][2] = {};
        #pragma unroll
        for (int ks = 0; ks < 4; ++ks) {
            bf16x8 a[2], b[2];
            #pragma unroll
            for (int m = 0; m < 2; ++m) {
                int row = wr * 32 + m * 16 + l15;
                int c16 = ks * 4 + l4;
                a[m] = *(const bf16x8*)(As + row * 128 + ((c16 ^ (row & 7)) * 8));
            }
            #pragma unroll
            for (int n = 0; n < 2; ++n) {
                int row = wc * 32 + n * 16 + l15;
                int c16 = ks * 4 + l4;
                b[n] = *(const bf16x8*)(Bs + row * 128 + ((c16 ^ (row & 7)) * 8));
            }
            #pragma unroll
            for (int m = 0; m < 2; ++m)
                #pragma unroll
                for (int n = 0; n < 2; ++n)
                    acc[m][n] = __builtin_amdgcn_mfma_f32_16x16x32_bf16(
                        a[m], b[n], acc[m][n], 0, 0, 0);
        }
        #pragma unroll
        for (int m = 0; m < 2; ++m)
            #pragma unroll
            for (int n = 0; n < 2; ++n)
                #pragma unroll
                for (int r = 0; r < 4; ++r) {
                    int grow = bm + wr * 32 + m * 16 + l4 * 4 + r;
                    int gcol = bn + wc * 32 + n * 16 + l15;
                    float val = acc[m][n][r] + bias[gcol];
                    int reg = gcol >> 7, lc = gcol & 127;
                    if (reg == 0)      qb[grow * D + lc] = f2bf(val * SQRT_D_INV);
                    else if (reg == 1) kb[grow * D + lc] = f2bf(val);
                    else               vT[(size_t)lc * N_PTS + grow] = f2bf(val);
                }
    } else if (bx < 246) {
        // Tcat convert: 150 blocks x 1024 elems
        int e0 = (bx - 96) * 1024 + tid * 4;
        int n = e0 >> 7, k = e0 & 127;
        int sec = n / QL, r = n - sec * QL;
        const float* t = (sec == 0) ? tx : ((sec == 1) ? ty : tz);
        float4 v = *(const float4*)&t[QL * D + r * D + k];
        ushort4 o;
        o.x = f2bf(v.x); o.y = f2bf(v.y); o.z = f2bf(v.z); o.w = f2bf(v.w);
        *(ushort4*)&Tcat[e0] = o;
    }

    grid_bar(barcnt, 1);

    // ================= P1: P GEMM, 304 tiles =================
    for (int t = bx; t < 304; t += NB) {
        __syncthreads();
        const int bm = (t / 19) * 64, bn = (t % 19) * 64;
        #pragma unroll
        for (int r = 0; r < 4; ++r) {
            int unit = r * 256 + tid;
            int row  = unit >> 4;
            int c16  = unit & 15;
            int csw  = c16 ^ (row & 7);
            const u16* ga = kb + (size_t)(bm + row) * D + csw * 8;
            __builtin_amdgcn_global_load_lds(
                (const GLOBAL_AS unsigned int*)ga,
                (LDS_AS unsigned int*)(As + r * 2048 + wave * 512), 16, 0, 0);
            int brow = bn + row; if (brow > PLD - 1) brow = PLD - 1;
            const u16* gb = Tcat + (size_t)brow * D + csw * 8;
            __builtin_amdgcn_global_load_lds(
                (const GLOBAL_AS unsigned int*)gb,
                (LDS_AS unsigned int*)(Bs + r * 2048 + wave * 512), 16, 0, 0);
        }
        __syncthreads();

        f32x4 acc[2][2] = {};
        #pragma unroll
        for (int ks = 0; ks < 4; ++ks) {
            bf16x8 a[2], b[2];
            #pragma unroll
            for (int m = 0; m < 2; ++m) {
                int row = wr * 32 + m * 16 + l15;
                int c16 = ks * 4 + l4;
                a[m] = *(const bf16x8*)(As + row * 128 + ((c16 ^ (row & 7)) * 8));
            }
            #pragma unroll
            for (int n = 0; n < 2; ++n) {
                int row = wc * 32 + n * 16 + l15;
                int c16 = ks * 4 + l4;
                b[n] = *(const bf16x8*)(Bs + row * 128 + ((c16 ^ (row & 7)) * 8));
            }
            #pragma unroll
            for (int m = 0; m < 2; ++m)
                #pragma unroll
                for (int n = 0; n < 2; ++n)
                    acc[m][n] = __builtin_amdgcn_mfma_f32_16x16x32_bf16(
                        a[m], b[n], acc[m][n], 0, 0, 0);
        }
        #pragma unroll
        for (int m = 0; m < 2; ++m)
            #pragma unroll
            for (int n = 0; n < 2; ++n)
                #pragma unroll
                for (int r = 0; r < 4; ++r) {
                    int grow = bm + wr * 32 + m * 16 + l4 * 4 + r;
                    int gcol = bn + wc * 32 + n * 16 + l15;
                    if (gcol < PLD)
                        Pb[(size_t)grow * PLD + gcol] = f2bf(acc[m][n][r] * SQRT_D_INV);
                }
    }

    grid_bar(barcnt, 2);

    // ================= P2: flash, 2 chunks per block =================
    {
        const int bi = bx >> 2;          // i-tile 0..63
        const int cp = bx & 3;           // chunk pair 0..3
        const int bm = bi * 16;

        // stage P slab (16 x 1200 bf16) once for both chunks
        const u16* Pg = Pb + (size_t)bm * PLD;
        #pragma unroll
        for (int r0 = 0; r0 < 9; ++r0) {
            int unit = r0 * 256 + tid;
            __builtin_amdgcn_global_load_lds(
                (const GLOBAL_AS unsigned int*)(Pg + unit * 8),
                (LDS_AS unsigned int*)(Pl + r0 * 2048 + wave * 512), 16, 0, 0);
        }
        if (wave < 2) {
            int unit = 9 * 256 + tid;
            int cu = unit > 2399 ? 2399 : unit;
            __builtin_amdgcn_global_load_lds(
                (const GLOBAL_AS unsigned int*)(Pg + cu * 8),
                (LDS_AS unsigned int*)(Pl + 9 * 2048 + wave * 512), 16, 0, 0);
        }

        // Q fragments: same rows for both chunks
        bf16x8 aq[4];
        #pragma unroll
        for (int ks = 0; ks < 4; ++ks)
            aq[ks] = *(const bf16x8*)(qb + (size_t)(bm + l15) * D + ks * 32 + l4 * 8);

        for (int cc = 0; cc < 2; ++cc) {
            const int chunk = cp * 2 + cc;
            const int bn = chunk * 128;

            // early vd loads
            float vx[2][4], vy[2][4], vz[2][4];
            #pragma unroll
            for (int nn = 0; nn < 2; ++nn)
                #pragma unroll
                for (int r = 0; r < 4; ++r) {
                    int i = l4 * 4 + r;
                    int j = wave * 32 + nn * 16 + l15;
                    const float* vp = vd + ((size_t)(bm + i) * N_PTS + bn + j) * 3;
                    vx[nn][r] = vp[0]; vy[nn][r] = vp[1]; vz[nn][r] = vp[2];
                }

            // QK^T
            f32x4 acc[2] = {};
            #pragma unroll
            for (int nn = 0; nn < 2; ++nn) {
                int jt = bn + wave * 32 + nn * 16;
                #pragma unroll
                for (int ks = 0; ks < 4; ++ks) {
                    bf16x8 bk = *(const bf16x8*)(kb + (size_t)(jt + l15) * D + ks * 32 + l4 * 8);
                    acc[nn] = __builtin_amdgcn_mfma_f32_16x16x32_bf16(aq[ks], bk, acc[nn], 0, 0, 0);
                }
            }
            __syncthreads();   // Pl staged (cc=0); Ps/rsw free (cc=1)

            // bias gather + exp + Ps + rowsum
            float rs[4] = {0.f, 0.f, 0.f, 0.f};
            #pragma unroll
            for (int nn = 0; nn < 2; ++nn)
                #pragma unroll
                for (int r = 0; r < 4; ++r) {
                    int i = l4 * 4 + r;
                    int jl = wave * 32 + nn * 16 + l15;
                    int ix = (int)floorf((vx[nn][r] + 4.0f) * 50.0f);
                    int iy = (int)floorf((vy[nn][r] + 4.0f) * 50.0f);
                    int iz = (int)floorf((vz[nn][r] + 4.0f) * 50.0f);
                    ix = min(max(ix, 0), QL - 1);
                    iy = min(max(iy, 0), QL - 1);
                    iz = min(max(iz, 0), QL - 1);
                    const u16* Pr = Pl + i * PLD;
                    float bv = b2f(Pr[ix]) + b2f(Pr[QL + iy]) + b2f(Pr[2 * QL + iz]);
                    float e = __expf(acc[nn][r] + bv);
                    rs[r] += e;
                    Ps[i * 128 + (((jl >> 3) ^ (i & 7)) * 8) + (jl & 7)] = f2bf(e);
                }
            #pragma unroll
            for (int r = 0; r < 4; ++r)
                #pragma unroll
                for (int off = 1; off < 16; off <<= 1)
                    rs[r] += __shfl_xor(rs[r], off);
            if (l15 == 0)
                #pragma unroll
                for (int r = 0; r < 4; ++r) rsw[wave * 16 + l4 * 4 + r] = rs[r];
            __syncthreads();
            if (tid < 16)
                rowsumP[chunk * N_PTS + bm + tid] =
                    rsw[tid] + rsw[16 + tid] + rsw[32 + tid] + rsw[48 + tid];

            // PV
            bf16x8 pa[4];
            #pragma unroll
            for (int kt = 0; kt < 4; ++kt)
                pa[kt] = *(const bf16x8*)(Ps + l15 * 128 + (((kt * 4 + l4) ^ (l15 & 7)) * 8));
            f32x4 acc2[2] = {};
            #pragma unroll
            for (int nn = 0; nn < 2; ++nn) {
                int dt = wave * 32 + nn * 16;
                #pragma unroll
                for (int kt = 0; kt < 4; ++kt) {
                    bf16x8 bv8 = *(const bf16x8*)(vT + (size_t)(dt + l15) * N_PTS + bn + kt * 32 + l4 * 8);
                    acc2[nn] = __builtin_amdgcn_mfma_f32_16x16x32_bf16(pa[kt], bv8, acc2[nn], 0, 0, 0);
                }
            }
            float* po = part + (size_t)chunk * (N_PTS * D);
            #pragma unroll
            for (int nn = 0; nn < 2; ++nn)
                #pragma unroll
                for (int r = 0; r < 4; ++r)
                    po[(size_t)(bm + l4 * 4 + r) * D + wave * 32 + nn * 16 + l15] = acc2[nn][r];
            __syncthreads();   // protect Ps before next chunk overwrites
        }
    }

    grid_bar(barcnt, 3);

    // ================= P3: reduce + normalize =================
    if (tid < 128) {
        int e = bx * 128 + tid;           // float4 id, 32768 total
        int row = e >> 5;
        float rsum = 0.0f;
        #pragma unroll
        for (int jb = 0; jb < 8; ++jb) rsum += rowsumP[jb * N_PTS + row];
        float inv = 1.0f / rsum;
        const float4* p4 = (const float4*)part;
        float4 a = p4[e];
        #pragma unroll
        for (int z = 1; z < 8; ++z) {
            float4 v = p4[(size_t)z * 32768 + e];
            a.x += v.x; a.y += v.y; a.z += v.z; a.w += v.w;
        }
        a.x *= inv; a.y *= inv; a.z *= inv; a.w *= inv;
        ((float4*)out)[e] = a;
    }
}

// ------------------------------------------------------------------
extern "C" void kernel_launch(void* const* d_in, const int* in_sizes, int n_in,
                              void* d_out, int out_size, void* d_ws, size_t ws_size,
                              hipStream_t stream)
{
    const float* features = (const float*)d_in[0];  // 1024 x 128
    const float* vd       = (const float*)d_in[1];  // 1024 x 1024 x 3
    const float* W        = (const float*)d_in[2];  // 128 x 384
    const float* b        = (const float*)d_in[3];  // 384
    const float* tx       = (const float*)d_in[4];  // 3 x 400 x 128
    const float* ty       = (const float*)d_in[5];
    const float* tz       = (const float*)d_in[6];
    float* out = (float*)d_out;                     // 1024 x 128 f32

    char* w0 = (char*)d_ws;
    unsigned* barcnt = (unsigned*)w0;               // 64 B barrier state
    u16* qb       = (u16*)(w0 + 0x1000);            // 256 KB
    u16* kb       = (u16*)(w0 + 0x50000);           // 256 KB
    u16* vT       = (u16*)(w0 + 0x90000);           // 256 KB (128x1024)
    u16* Tcat     = (u16*)(w0 + 0xD0000);           // 300 KB
    u16* Pb       = (u16*)(w0 + 0x120000);          // 2.4 MB (1024x1200 bf16)
    float* part   = (float*)(w0 + 0x380000);        // 4 MB   [8][1024][128]
    float* rowsumP= (float*)(w0 + 0x780000);        // 32 KB  [8][1024]

    // barrier state must be 0 at kernel start, every call (ws is poisoned once)
    hipMemsetAsync(barcnt, 0, 64, stream);

    mega_kernel<<<dim3(NB), dim3(256), 0, stream>>>(
        features, W, b, tx, ty, tz, vd,
        qb, kb, vT, Tcat, Pb, part, rowsumP, out, barcnt);
}

// Round 7
// 91.793 us; speedup vs baseline: 1.0780x; 1.0780x over previous
//
#include <hip/hip_runtime.h>
#include <math.h>

#define N_PTS 1024
#define D 128
#define QL 400
#define PLD 1200            // 3*QL
#define SQRT_D_INV 0.08838834764831845f

typedef __attribute__((ext_vector_type(8))) short bf16x8;
typedef __attribute__((ext_vector_type(4))) float f32x4;
typedef unsigned short u16;

#define GLOBAL_AS __attribute__((address_space(1)))
#define LDS_AS    __attribute__((address_space(3)))

__device__ __forceinline__ u16 f2bf(float x) {
    union { float f; unsigned u; } v; v.f = x;
    unsigned r = v.u + 0x7fff + ((v.u >> 16) & 1);   // RNE
    return (u16)(r >> 16);
}
__device__ __forceinline__ float b2f(u16 h) {
    union { unsigned u; float f; } v; v.u = ((unsigned)h) << 16;
    return v.f;
}

// ------------------------------------------------------------------
// prep_kernel: blocks [0,96): qkv = features @ W + bias -> qb(1/sqrtD)/kb/vT
//              blocks [96,246): convert tables[1] -> Tcat bf16
// ------------------------------------------------------------------
__global__ __launch_bounds__(256) void prep_kernel(
    const float* __restrict__ features, const float* __restrict__ W,
    const float* __restrict__ bias,
    const float* __restrict__ tx, const float* __restrict__ ty,
    const float* __restrict__ tz,
    u16* __restrict__ qb, u16* __restrict__ kb, u16* __restrict__ vT,
    u16* __restrict__ Tcat)
{
    __shared__ __align__(16) u16 As[64 * 128];
    __shared__ __align__(16) u16 Bs[64 * 128];
    const int tid = threadIdx.x;
    const int bx = blockIdx.x;

    if (bx >= 96) {
        int e0 = (bx - 96) * 1024 + tid * 4;
        int n = e0 >> 7, k = e0 & 127;
        int sec = n / QL, r = n - sec * QL;
        const float* t = (sec == 0) ? tx : ((sec == 1) ? ty : tz);
        float4 v = *(const float4*)&t[QL * D + r * D + k];
        ushort4 o;
        o.x = f2bf(v.x); o.y = f2bf(v.y); o.z = f2bf(v.z); o.w = f2bf(v.w);
        *(ushort4*)&Tcat[e0] = o;
        return;
    }

    const int wave = tid >> 6, lane = tid & 63;
    const int wr = wave >> 1, wc = wave & 1;
    const int l15 = lane & 15, l4 = lane >> 4;
    const int bm = (bx / 6) * 64;
    const int bn = (bx % 6) * 64;

    #pragma unroll
    for (int r0 = 0; r0 < 4; ++r0) {
        int unit = r0 * 256 + tid;
        int row = unit >> 4, c16 = unit & 15;
        const float* ga = features + (size_t)(bm + row) * D + c16 * 8;
        float4 a0 = *(const float4*)ga;
        float4 a1 = *(const float4*)(ga + 4);
        u16 h[8] = {f2bf(a0.x), f2bf(a0.y), f2bf(a0.z), f2bf(a0.w),
                    f2bf(a1.x), f2bf(a1.y), f2bf(a1.z), f2bf(a1.w)};
        *(bf16x8*)(As + row * 128 + ((c16 ^ (row & 7)) * 8)) = *(bf16x8*)h;
    }
    #pragma unroll
    for (int r2 = 0; r2 < 8; ++r2) {
        int k = r2 * 16 + (tid >> 4);
        int nl = (tid & 15) * 4;
        float4 w4 = *(const float4*)&W[(size_t)k * 384 + bn + nl];
        float wv[4] = {w4.x, w4.y, w4.z, w4.w};
        #pragma unroll
        for (int e = 0; e < 4; ++e) {
            int n = nl + e;
            Bs[n * 128 + (((k >> 3) ^ (n & 7)) << 3) + (k & 7)] = f2bf(wv[e]);
        }
    }
    __syncthreads();

    f32x4 acc[2][2] = {};
    #pragma unroll
    for (int ks = 0; ks < 4; ++ks) {
        bf16x8 a[2], b[2];
        #pragma unroll
        for (int m = 0; m < 2; ++m) {
            int row = wr * 32 + m * 16 + l15;
            int c16 = ks * 4 + l4;
            a[m] = *(const bf16x8*)(As + row * 128 + ((c16 ^ (row & 7)) * 8));
        }
        #pragma unroll
        for (int n = 0; n < 2; ++n) {
            int row = wc * 32 + n * 16 + l15;
            int c16 = ks * 4 + l4;
            b[n] = *(const bf16x8*)(Bs + row * 128 + ((c16 ^ (row & 7)) * 8));
        }
        #pragma unroll
        for (int m = 0; m < 2; ++m)
            #pragma unroll
            for (int n = 0; n < 2; ++n)
                acc[m][n] = __builtin_amdgcn_mfma_f32_16x16x32_bf16(
                    a[m], b[n], acc[m][n], 0, 0, 0);
    }

    #pragma unroll
    for (int m = 0; m < 2; ++m)
        #pragma unroll
        for (int n = 0; n < 2; ++n)
            #pragma unroll
            for (int r = 0; r < 4; ++r) {
                int grow = bm + wr * 32 + m * 16 + l4 * 4 + r;
                int gcol = bn + wc * 32 + n * 16 + l15;
                float val = acc[m][n][r] + bias[gcol];
                int reg = gcol >> 7, lc = gcol & 127;
                if (reg == 0)      qb[grow * D + lc] = f2bf(val * SQRT_D_INV);
                else if (reg == 1) kb[grow * D + lc] = f2bf(val);
                else               vT[(size_t)lc * N_PTS + grow] = f2bf(val);
            }
}

// ------------------------------------------------------------------
// P GEMM: Pb = (kb @ Tcat^T)*1/sqrt(D), bf16. Also zeroes cnt[64]
// (stream-ordered: runs strictly before flash).
// ------------------------------------------------------------------
__global__ __launch_bounds__(256) void p_gemm_kernel(
    const u16* __restrict__ A,      // kb 1024x128
    const u16* __restrict__ B,      // Tcat 1200x128
    u16* __restrict__ Cb,           // Pb 1024x1200 bf16
    unsigned* __restrict__ cnt)     // [64] last-arriver counters (zeroed here)
{
    __shared__ __align__(16) u16 As[64 * 128];
    __shared__ __align__(16) u16 Bs[64 * 128];
    const int tid  = threadIdx.x;
    if (blockIdx.x == 0 && blockIdx.y == 0 && tid < 64) cnt[tid] = 0u;
    const int wave = tid >> 6, lane = tid & 63;
    const int wr = wave >> 1, wc = wave & 1;
    const int l15 = lane & 15, l4 = lane >> 4;
    const int bm = blockIdx.y * 64, bn = blockIdx.x * 64;

    #pragma unroll
    for (int r = 0; r < 4; ++r) {
        int unit = r * 256 + tid;
        int row  = unit >> 4;
        int c16  = unit & 15;
        int csw  = c16 ^ (row & 7);
        const u16* ga = A + (size_t)(bm + row) * D + csw * 8;
        __builtin_amdgcn_global_load_lds(
            (const GLOBAL_AS unsigned int*)ga,
            (LDS_AS unsigned int*)(As + r * 2048 + wave * 512), 16, 0, 0);
        int brow = bn + row; if (brow > PLD - 1) brow = PLD - 1;
        const u16* gb = B + (size_t)brow * D + csw * 8;
        __builtin_amdgcn_global_load_lds(
            (const GLOBAL_AS unsigned int*)gb,
            (LDS_AS unsigned int*)(Bs + r * 2048 + wave * 512), 16, 0, 0);
    }
    __syncthreads();

    f32x4 acc[2][2] = {};
    #pragma unroll
    for (int ks = 0; ks < 4; ++ks) {
        bf16x8 a[2], b[2];
        #pragma unroll
        for (int m = 0; m < 2; ++m) {
            int row = wr * 32 + m * 16 + l15;
            int c16 = ks * 4 + l4;
            a[m] = *(const bf16x8*)(As + row * 128 + ((c16 ^ (row & 7)) * 8));
        }
        #pragma unroll
        for (int n = 0; n < 2; ++n) {
            int row = wc * 32 + n * 16 + l15;
            int c16 = ks * 4 + l4;
            b[n] = *(const bf16x8*)(Bs + row * 128 + ((c16 ^ (row & 7)) * 8));
        }
        #pragma unroll
        for (int m = 0; m < 2; ++m)
            #pragma unroll
            for (int n = 0; n < 2; ++n)
                acc[m][n] = __builtin_amdgcn_mfma_f32_16x16x32_bf16(
                    a[m], b[n], acc[m][n], 0, 0, 0);
    }

    #pragma unroll
    for (int m = 0; m < 2; ++m)
        #pragma unroll
        for (int n = 0; n < 2; ++n)
            #pragma unroll
            for (int r = 0; r < 4; ++r) {
                int grow = bm + wr * 32 + m * 16 + l4 * 4 + r;
                int gcol = bn + wc * 32 + n * 16 + l15;
                if (gcol < PLD)
                    Cb[(size_t)grow * PLD + gcol] = f2bf(acc[m][n][r] * SQRT_D_INV);
            }
}

// ------------------------------------------------------------------
// flash_kernel: grid (64 i-tiles, 8 j-chunks). Per block: P-slab LDS,
// QK^T MFMA, bias gather, exp, PV MFMA -> tile-local partials.
// Last-arriving chunk-block of each i-tile reduces+normalizes -> out.
// ------------------------------------------------------------------
__global__ __launch_bounds__(256) void flash_kernel(
    const u16* __restrict__ qb,   // 1024x128 (pre-scaled)
    const u16* __restrict__ kb,   // 1024x128
    const u16* __restrict__ vT,   // 128x1024
    const u16* __restrict__ Pb,   // 1024x1200 bf16 (pre-scaled)
    const float* __restrict__ vd, // 1024x1024x3
    float* __restrict__ part,     // [64][8][16][128]
    float* __restrict__ rowsumC,  // [64][8][16]
    unsigned* __restrict__ cnt,   // [64]
    float* __restrict__ out)      // [1024][128]
{
    __shared__ __align__(16) u16 Pl[2432 * 8];   // 16x1200 + pad
    __shared__ __align__(16) u16 Ps[16 * 128];
    __shared__ float rsw[4][16];
    __shared__ int lastflag;
    const int tid = threadIdx.x;
    const int wave = tid >> 6, lane = tid & 63;
    const int l15 = lane & 15, l4 = lane >> 4;
    const int it = blockIdx.x;          // i tile 0..63
    const int chunk = blockIdx.y;       // 0..7
    const int bm = it * 16;
    const int bn = chunk * 128;

    // ---- stage P slab ----
    const u16* Pg = Pb + (size_t)bm * PLD;
    #pragma unroll
    for (int r0 = 0; r0 < 9; ++r0) {
        int unit = r0 * 256 + tid;
        __builtin_amdgcn_global_load_lds(
            (const GLOBAL_AS unsigned int*)(Pg + unit * 8),
            (LDS_AS unsigned int*)(Pl + r0 * 2048 + wave * 512), 16, 0, 0);
    }
    if (wave < 2) {
        int unit = 9 * 256 + tid;
        int cu = unit > 2399 ? 2399 : unit;
        __builtin_amdgcn_global_load_lds(
            (const GLOBAL_AS unsigned int*)(Pg + cu * 8),
            (LDS_AS unsigned int*)(Pl + 9 * 2048 + wave * 512), 16, 0, 0);
    }

    // ---- early vd loads ----
    float vx[2][4], vy[2][4], vz[2][4];
    #pragma unroll
    for (int nn = 0; nn < 2; ++nn)
        #pragma unroll
        for (int r = 0; r < 4; ++r) {
            int i = l4 * 4 + r;
            int j = wave * 32 + nn * 16 + l15;
            const float* vp = vd + ((size_t)(bm + i) * N_PTS + bn + j) * 3;
            vx[nn][r] = vp[0]; vy[nn][r] = vp[1]; vz[nn][r] = vp[2];
        }

    // ---- QK^T ----
    bf16x8 aq[4];
    #pragma unroll
    for (int ks = 0; ks < 4; ++ks)
        aq[ks] = *(const bf16x8*)(qb + (size_t)(bm + l15) * D + ks * 32 + l4 * 8);
    f32x4 acc[2] = {};
    #pragma unroll
    for (int nn = 0; nn < 2; ++nn) {
        int jt = bn + wave * 32 + nn * 16;
        #pragma unroll
        for (int ks = 0; ks < 4; ++ks) {
            bf16x8 bk = *(const bf16x8*)(kb + (size_t)(jt + l15) * D + ks * 32 + l4 * 8);
            acc[nn] = __builtin_amdgcn_mfma_f32_16x16x32_bf16(aq[ks], bk, acc[nn], 0, 0, 0);
        }
    }
    __syncthreads();   // Pl staged

    // ---- bias gather + exp + Ps + rowsum ----
    float rs[4] = {0.f, 0.f, 0.f, 0.f};
    #pragma unroll
    for (int nn = 0; nn < 2; ++nn)
        #pragma unroll
        for (int r = 0; r < 4; ++r) {
            int i = l4 * 4 + r;
            int jl = wave * 32 + nn * 16 + l15;
            int ix = (int)floorf((vx[nn][r] + 4.0f) * 50.0f);
            int iy = (int)floorf((vy[nn][r] + 4.0f) * 50.0f);
            int iz = (int)floorf((vz[nn][r] + 4.0f) * 50.0f);
            ix = min(max(ix, 0), QL - 1);
            iy = min(max(iy, 0), QL - 1);
            iz = min(max(iz, 0), QL - 1);
            const u16* Pr = Pl + i * PLD;
            float bv = b2f(Pr[ix]) + b2f(Pr[QL + iy]) + b2f(Pr[2 * QL + iz]);
            float e = __expf(acc[nn][r] + bv);
            rs[r] += e;
            Ps[i * 128 + (((jl >> 3) ^ (i & 7)) * 8) + (jl & 7)] = f2bf(e);
        }
    #pragma unroll
    for (int r = 0; r < 4; ++r)
        #pragma unroll
        for (int off = 1; off < 16; off <<= 1)
            rs[r] += __shfl_xor(rs[r], off);
    if (l15 == 0)
        #pragma unroll
        for (int r = 0; r < 4; ++r) rsw[wave][l4 * 4 + r] = rs[r];
    __syncthreads();
    if (tid < 16)
        rowsumC[(it * 8 + chunk) * 16 + tid] =
            rsw[0][tid] + rsw[1][tid] + rsw[2][tid] + rsw[3][tid];

    // ---- PV ----
    bf16x8 pa[4];
    #pragma unroll
    for (int kt = 0; kt < 4; ++kt)
        pa[kt] = *(const bf16x8*)(Ps + l15 * 128 + (((kt * 4 + l4) ^ (l15 & 7)) * 8));
    f32x4 acc2[2] = {};
    #pragma unroll
    for (int nn = 0; nn < 2; ++nn) {
        int dt = wave * 32 + nn * 16;
        #pragma unroll
        for (int kt = 0; kt < 4; ++kt) {
            bf16x8 bv8 = *(const bf16x8*)(vT + (size_t)(dt + l15) * N_PTS + bn + kt * 32 + l4 * 8);
            acc2[nn] = __builtin_amdgcn_mfma_f32_16x16x32_bf16(pa[kt], bv8, acc2[nn], 0, 0, 0);
        }
    }
    float* po = part + (size_t)(it * 8 + chunk) * (16 * D);
    #pragma unroll
    for (int nn = 0; nn < 2; ++nn)
        #pragma unroll
        for (int r = 0; r < 4; ++r)
            po[(l4 * 4 + r) * D + wave * 32 + nn * 16 + l15] = acc2[nn][r];

    // ---- last-arriver reduce+normalize (no waiting) ----
    __threadfence();           // release partials+rowsums (agent scope)
    __syncthreads();
    if (tid == 0) {
        unsigned old = __hip_atomic_fetch_add(
            &cnt[it], 1u, __ATOMIC_ACQ_REL, __HIP_MEMORY_SCOPE_AGENT);
        lastflag = (old == 7u);
    }
    __syncthreads();
    if (lastflag) {
        __threadfence();       // acquire: see all 8 chunks' writes
        const float4* p4 = (const float4*)(part + (size_t)it * 8 * 16 * D);
        const float* rsb = rowsumC + it * 8 * 16;
        #pragma unroll
        for (int h = 0; h < 2; ++h) {
            int f4 = h * 256 + tid;            // 0..511 (16 rows x 32 f4)
            int row = f4 >> 5;
            float rsum = 0.0f;
            #pragma unroll
            for (int z = 0; z < 8; ++z) rsum += rsb[z * 16 + row];
            float inv = 1.0f / rsum;
            float4 a = p4[f4];
            #pragma unroll
            for (int z = 1; z < 8; ++z) {
                float4 v = p4[z * 512 + f4];
                a.x += v.x; a.y += v.y; a.z += v.z; a.w += v.w;
            }
            a.x *= inv; a.y *= inv; a.z *= inv; a.w *= inv;
            ((float4*)out)[bm * 32 + f4] = a;
        }
    }
}

// ------------------------------------------------------------------
extern "C" void kernel_launch(void* const* d_in, const int* in_sizes, int n_in,
                              void* d_out, int out_size, void* d_ws, size_t ws_size,
                              hipStream_t stream)
{
    const float* features = (const float*)d_in[0];  // 1024 x 128
    const float* vd       = (const float*)d_in[1];  // 1024 x 1024 x 3
    const float* W        = (const float*)d_in[2];  // 128 x 384
    const float* b        = (const float*)d_in[3];  // 384
    const float* tx       = (const float*)d_in[4];  // 3 x 400 x 128
    const float* ty       = (const float*)d_in[5];
    const float* tz       = (const float*)d_in[6];
    float* out = (float*)d_out;                     // 1024 x 128 f32

    char* w0 = (char*)d_ws;
    unsigned* cnt = (unsigned*)w0;                  // 256 B  [64]
    u16* qb       = (u16*)(w0 + 0x1000);            // 256 KB
    u16* kb       = (u16*)(w0 + 0x50000);           // 256 KB
    u16* vT       = (u16*)(w0 + 0x90000);           // 256 KB (128x1024)
    u16* Tcat     = (u16*)(w0 + 0xD0000);           // 300 KB
    u16* Pb       = (u16*)(w0 + 0x120000);          // 2.4 MB (1024x1200 bf16)
    float* part   = (float*)(w0 + 0x380000);        // 4 MB   [64][8][16][128]
    float* rowsumC= (float*)(w0 + 0x780000);        // 32 KB  [64][8][16]

    dim3 blk(256);

    // 1. qkv (+bias, q pre-scaled) + Tcat convert
    prep_kernel<<<dim3(246), blk, 0, stream>>>(
        features, W, b, tx, ty, tz, qb, kb, vT, Tcat);

    // 2. Pb GEMM (also zeroes cnt before flash)
    p_gemm_kernel<<<dim3(19, 16), blk, 0, stream>>>(kb, Tcat, Pb, cnt);

    // 3. flash + last-arriver reduce/normalize
    flash_kernel<<<dim3(64, 8), blk, 0, stream>>>(
        qb, kb, vT, Pb, vd, part, rowsumC, cnt, out);
}

// Round 8
// 36.692 us; speedup vs baseline: 2.6968x; 2.5017x over previous
//
#include <hip/hip_runtime.h>
#include <math.h>

#define N_PTS 1024
#define D 128
#define QL 400
#define PLD 1200            // 3*QL
#define SQRT_D_INV 0.08838834764831845f

typedef __attribute__((ext_vector_type(8))) short bf16x8;
typedef __attribute__((ext_vector_type(4))) float f32x4;
typedef unsigned short u16;

#define GLOBAL_AS __attribute__((address_space(1)))
#define LDS_AS    __attribute__((address_space(3)))

__device__ __forceinline__ u16 f2bf(float x) {
    union { float f; unsigned u; } v; v.f = x;
    unsigned r = v.u + 0x7fff + ((v.u >> 16) & 1);   // RNE
    return (u16)(r >> 16);
}
__device__ __forceinline__ float b2f(u16 h) {
    union { unsigned u; float f; } v; v.u = ((unsigned)h) << 16;
    return v.f;
}

// ------------------------------------------------------------------
// prep_kernel: blocks [0,96): qkv = features @ W + bias -> qb(1/sqrtD)/kb/vT
//              blocks [96,246): convert tables[1] -> Tcat bf16
// (identical to R4's proven version)
// ------------------------------------------------------------------
__global__ __launch_bounds__(256) void prep_kernel(
    const float* __restrict__ features, const float* __restrict__ W,
    const float* __restrict__ bias,
    const float* __restrict__ tx, const float* __restrict__ ty,
    const float* __restrict__ tz,
    u16* __restrict__ qb, u16* __restrict__ kb, u16* __restrict__ vT,
    u16* __restrict__ Tcat)
{
    __shared__ __align__(16) u16 As[64 * 128];
    __shared__ __align__(16) u16 Bs[64 * 128];
    const int tid = threadIdx.x;
    const int bx = blockIdx.x;

    if (bx >= 96) {
        int e0 = (bx - 96) * 1024 + tid * 4;
        int n = e0 >> 7, k = e0 & 127;
        int sec = n / QL, r = n - sec * QL;
        const float* t = (sec == 0) ? tx : ((sec == 1) ? ty : tz);
        float4 v = *(const float4*)&t[QL * D + r * D + k];
        ushort4 o;
        o.x = f2bf(v.x); o.y = f2bf(v.y); o.z = f2bf(v.z); o.w = f2bf(v.w);
        *(ushort4*)&Tcat[e0] = o;
        return;
    }

    const int wave = tid >> 6, lane = tid & 63;
    const int wr = wave >> 1, wc = wave & 1;
    const int l15 = lane & 15, l4 = lane >> 4;
    const int bm = (bx / 6) * 64;
    const int bn = (bx % 6) * 64;

    #pragma unroll
    for (int r0 = 0; r0 < 4; ++r0) {
        int unit = r0 * 256 + tid;
        int row = unit >> 4, c16 = unit & 15;
        const float* ga = features + (size_t)(bm + row) * D + c16 * 8;
        float4 a0 = *(const float4*)ga;
        float4 a1 = *(const float4*)(ga + 4);
        u16 h[8] = {f2bf(a0.x), f2bf(a0.y), f2bf(a0.z), f2bf(a0.w),
                    f2bf(a1.x), f2bf(a1.y), f2bf(a1.z), f2bf(a1.w)};
        *(bf16x8*)(As + row * 128 + ((c16 ^ (row & 7)) * 8)) = *(bf16x8*)h;
    }
    #pragma unroll
    for (int r2 = 0; r2 < 8; ++r2) {
        int k = r2 * 16 + (tid >> 4);
        int nl = (tid & 15) * 4;
        float4 w4 = *(const float4*)&W[(size_t)k * 384 + bn + nl];
        float wv[4] = {w4.x, w4.y, w4.z, w4.w};
        #pragma unroll
        for (int e = 0; e < 4; ++e) {
            int n = nl + e;
            Bs[n * 128 + (((k >> 3) ^ (n & 7)) << 3) + (k & 7)] = f2bf(wv[e]);
        }
    }
    __syncthreads();

    f32x4 acc[2][2] = {};
    #pragma unroll
    for (int ks = 0; ks < 4; ++ks) {
        bf16x8 a[2], b[2];
        #pragma unroll
        for (int m = 0; m < 2; ++m) {
            int row = wr * 32 + m * 16 + l15;
            int c16 = ks * 4 + l4;
            a[m] = *(const bf16x8*)(As + row * 128 + ((c16 ^ (row & 7)) * 8));
        }
        #pragma unroll
        for (int n = 0; n < 2; ++n) {
            int row = wc * 32 + n * 16 + l15;
            int c16 = ks * 4 + l4;
            b[n] = *(const bf16x8*)(Bs + row * 128 + ((c16 ^ (row & 7)) * 8));
        }
        #pragma unroll
        for (int m = 0; m < 2; ++m)
            #pragma unroll
            for (int n = 0; n < 2; ++n)
                acc[m][n] = __builtin_amdgcn_mfma_f32_16x16x32_bf16(
                    a[m], b[n], acc[m][n], 0, 0, 0);
    }

    #pragma unroll
    for (int m = 0; m < 2; ++m)
        #pragma unroll
        for (int n = 0; n < 2; ++n)
            #pragma unroll
            for (int r = 0; r < 4; ++r) {
                int grow = bm + wr * 32 + m * 16 + l4 * 4 + r;
                int gcol = bn + wc * 32 + n * 16 + l15;
                float val = acc[m][n][r] + bias[gcol];
                int reg = gcol >> 7, lc = gcol & 127;
                if (reg == 0)      qb[grow * D + lc] = f2bf(val * SQRT_D_INV);
                else if (reg == 1) kb[grow * D + lc] = f2bf(val);
                else               vT[(size_t)lc * N_PTS + grow] = f2bf(val);
            }
}

// ------------------------------------------------------------------
// P GEMM: Pb = (kb @ Tcat^T)*1/sqrt(D), bf16 (R4-proven, cnt removed)
// ------------------------------------------------------------------
__global__ __launch_bounds__(256) void p_gemm_kernel(
    const u16* __restrict__ A,      // kb 1024x128
    const u16* __restrict__ B,      // Tcat 1200x128
    u16* __restrict__ Cb)           // Pb 1024x1200 bf16
{
    __shared__ __align__(16) u16 As[64 * 128];
    __shared__ __align__(16) u16 Bs[64 * 128];
    const int tid  = threadIdx.x;
    const int wave = tid >> 6, lane = tid & 63;
    const int wr = wave >> 1, wc = wave & 1;
    const int l15 = lane & 15, l4 = lane >> 4;
    const int bm = blockIdx.y * 64, bn = blockIdx.x * 64;

    #pragma unroll
    for (int r = 0; r < 4; ++r) {
        int unit = r * 256 + tid;
        int row  = unit >> 4;
        int c16  = unit & 15;
        int csw  = c16 ^ (row & 7);
        const u16* ga = A + (size_t)(bm + row) * D + csw * 8;
        __builtin_amdgcn_global_load_lds(
            (const GLOBAL_AS unsigned int*)ga,
            (LDS_AS unsigned int*)(As + r * 2048 + wave * 512), 16, 0, 0);
        int brow = bn + row; if (brow > PLD - 1) brow = PLD - 1;
        const u16* gb = B + (size_t)brow * D + csw * 8;
        __builtin_amdgcn_global_load_lds(
            (const GLOBAL_AS unsigned int*)gb,
            (LDS_AS unsigned int*)(Bs + r * 2048 + wave * 512), 16, 0, 0);
    }
    __syncthreads();

    f32x4 acc[2][2] = {};
    #pragma unroll
    for (int ks = 0; ks < 4; ++ks) {
        bf16x8 a[2], b[2];
        #pragma unroll
        for (int m = 0; m < 2; ++m) {
            int row = wr * 32 + m * 16 + l15;
            int c16 = ks * 4 + l4;
            a[m] = *(const bf16x8*)(As + row * 128 + ((c16 ^ (row & 7)) * 8));
        }
        #pragma unroll
        for (int n = 0; n < 2; ++n) {
            int row = wc * 32 + n * 16 + l15;
            int c16 = ks * 4 + l4;
            b[n] = *(const bf16x8*)(Bs + row * 128 + ((c16 ^ (row & 7)) * 8));
        }
        #pragma unroll
        for (int m = 0; m < 2; ++m)
            #pragma unroll
            for (int n = 0; n < 2; ++n)
                acc[m][n] = __builtin_amdgcn_mfma_f32_16x16x32_bf16(
                    a[m], b[n], acc[m][n], 0, 0, 0);
    }

    #pragma unroll
    for (int m = 0; m < 2; ++m)
        #pragma unroll
        for (int n = 0; n < 2; ++n)
            #pragma unroll
            for (int r = 0; r < 4; ++r) {
                int grow = bm + wr * 32 + m * 16 + l4 * 4 + r;
                int gcol = bn + wc * 32 + n * 16 + l15;
                if (gcol < PLD)
                    Cb[(size_t)grow * PLD + gcol] = f2bf(acc[m][n][r] * SQRT_D_INV);
            }
}

// ------------------------------------------------------------------
// flash_online: 256 blocks x 512 threads. Block owns 4 q-rows, sweeps
// ALL j. Rows replicated 4x in 16-row MFMA fragments (compute is cheap).
// Per wave w: QK+exp for j in [w*128,(w+1)*128) in 2 passes of 64;
// Ps (4x1024 bf16, stride 1032 for bank spread) holds exp weights;
// PV: wave w owns d-slice [w*16,(w+1)*16), full K=1024.
// Output written directly, normalized. NO partials/atomics/fences.
// ------------------------------------------------------------------
__global__ __launch_bounds__(512) void flash_online_kernel(
    const u16* __restrict__ qb,   // 1024x128 (pre-scaled)
    const u16* __restrict__ kb,   // 1024x128
    const u16* __restrict__ vT,   // 128x1024
    const u16* __restrict__ Pb,   // 1024x1200 bf16 (pre-scaled)
    const float* __restrict__ vd, // 1024x1024x3
    float* __restrict__ out)      // 1024x128 f32
{
    __shared__ __align__(16) u16 Pl[4800];       // 4 x 1200
    __shared__ __align__(16) u16 Ps[4 * 1032];   // padded stride (bank spread)
    __shared__ float rsum8[8][4];

    const int tid = threadIdx.x;
    const int w = tid >> 6, lane = tid & 63;
    const int l15 = lane & 15, l4 = lane >> 4;
    const int bm = blockIdx.x * 4;

    // ---- stage P slab: 600 16B-units ----
    const u16* Pg = Pb + (size_t)bm * PLD;
    {
        __builtin_amdgcn_global_load_lds(
            (const GLOBAL_AS unsigned int*)(Pg + tid * 8),
            (LDS_AS unsigned int*)(Pl + w * 512), 16, 0, 0);
        int unit = 512 + tid;
        if (unit < 600)
            __builtin_amdgcn_global_load_lds(
                (const GLOBAL_AS unsigned int*)(Pg + unit * 8),
                (LDS_AS unsigned int*)(Pl + 4096 + w * 512), 16, 0, 0);
    }

    // ---- Q fragments (rows replicated: real row = l15 & 3) ----
    bf16x8 aq[4];
    #pragma unroll
    for (int ks = 0; ks < 4; ++ks)
        aq[ks] = *(const bf16x8*)(qb + (size_t)(bm + (l15 & 3)) * D + ks * 32 + l4 * 8);

    float rsacc[4] = {0.f, 0.f, 0.f, 0.f};

    // ---- pass 0: vd + QK issued before the barrier (overlap staging) ----
    float vx[4][4], vy[4][4], vz[4][4];
    f32x4 acc[4];
    int jbase = w * 128;
    #pragma unroll
    for (int nn = 0; nn < 4; ++nn)
        #pragma unroll
        for (int r = 0; r < 4; ++r) {
            const float* vp = vd + ((size_t)(bm + r) * N_PTS + jbase + nn * 16 + l15) * 3;
            vx[nn][r] = vp[0]; vy[nn][r] = vp[1]; vz[nn][r] = vp[2];
        }
    #pragma unroll
    for (int nn = 0; nn < 4; ++nn) {
        acc[nn] = (f32x4){0.f, 0.f, 0.f, 0.f};
        #pragma unroll
        for (int ks = 0; ks < 4; ++ks) {
            bf16x8 bk = *(const bf16x8*)(kb + (size_t)(jbase + nn * 16 + l15) * D + ks * 32 + l4 * 8);
            acc[nn] = __builtin_amdgcn_mfma_f32_16x16x32_bf16(aq[ks], bk, acc[nn], 0, 0, 0);
        }
    }
    __syncthreads();   // Pl staged (drains global_load_lds)

    #pragma unroll
    for (int p = 0; p < 2; ++p) {
        if (p == 1) {
            jbase = w * 128 + 64;
            #pragma unroll
            for (int nn = 0; nn < 4; ++nn)
                #pragma unroll
                for (int r = 0; r < 4; ++r) {
                    const float* vp = vd + ((size_t)(bm + r) * N_PTS + jbase + nn * 16 + l15) * 3;
                    vx[nn][r] = vp[0]; vy[nn][r] = vp[1]; vz[nn][r] = vp[2];
                }
            #pragma unroll
            for (int nn = 0; nn < 4; ++nn) {
                acc[nn] = (f32x4){0.f, 0.f, 0.f, 0.f};
                #pragma unroll
                for (int ks = 0; ks < 4; ++ks) {
                    bf16x8 bk = *(const bf16x8*)(kb + (size_t)(jbase + nn * 16 + l15) * D + ks * 32 + l4 * 8);
                    acc[nn] = __builtin_amdgcn_mfma_f32_16x16x32_bf16(aq[ks], bk, acc[nn], 0, 0, 0);
                }
            }
        }
        // bias gather + exp + Ps write + rowsum (rows replicated over l4; writes gated)
        #pragma unroll
        for (int nn = 0; nn < 4; ++nn)
            #pragma unroll
            for (int r = 0; r < 4; ++r) {
                int j = jbase + nn * 16 + l15;
                int ix = (int)floorf((vx[nn][r] + 4.0f) * 50.0f);
                int iy = (int)floorf((vy[nn][r] + 4.0f) * 50.0f);
                int iz = (int)floorf((vz[nn][r] + 4.0f) * 50.0f);
                ix = min(max(ix, 0), QL - 1);
                iy = min(max(iy, 0), QL - 1);
                iz = min(max(iz, 0), QL - 1);
                const u16* Pr = Pl + r * PLD;
                float bv = b2f(Pr[ix]) + b2f(Pr[QL + iy]) + b2f(Pr[2 * QL + iz]);
                float e = __expf(acc[r & 3 ? (nn) : (nn)][r] + bv);   // acc[nn][r]
                e = __expf(acc[nn][r] + bv) == e ? e : e;             // (keep simple)
                e = __expf(acc[nn][r] + bv);
                rsacc[r] += e;
                if (l4 == 0) Ps[r * 1032 + j] = f2bf(e);
            }
    }

    // ---- rowsum reduce: over l15 (j) then across waves via LDS ----
    #pragma unroll
    for (int r = 0; r < 4; ++r)
        #pragma unroll
        for (int off = 1; off < 16; off <<= 1)
            rsacc[r] += __shfl_xor(rsacc[r], off);
    if (lane == 0)
        #pragma unroll
        for (int r = 0; r < 4; ++r) rsum8[w][r] = rsacc[r];
    __syncthreads();   // Ps + rsum8 ready

    float rtot[4];
    #pragma unroll
    for (int r = 0; r < 4; ++r) {
        float s = 0.f;
        #pragma unroll
        for (int z = 0; z < 8; ++z) s += rsum8[z][r];
        rtot[r] = 1.0f / s;
    }

    // ---- PV: wave w owns d-slice [w*16, w*16+16), K = 1024 (2 chains) ----
    const int dt = w * 16;
    f32x4 a2a = {0.f, 0.f, 0.f, 0.f}, a2b = {0.f, 0.f, 0.f, 0.f};
    #pragma unroll
    for (int kt = 0; kt < 32; kt += 2) {
        bf16x8 pa0 = *(const bf16x8*)(Ps + (l15 & 3) * 1032 + kt * 32 + l4 * 8);
        bf16x8 bv0 = *(const bf16x8*)(vT + (size_t)(dt + l15) * N_PTS + kt * 32 + l4 * 8);
        a2a = __builtin_amdgcn_mfma_f32_16x16x32_bf16(pa0, bv0, a2a, 0, 0, 0);
        bf16x8 pa1 = *(const bf16x8*)(Ps + (l15 & 3) * 1032 + (kt + 1) * 32 + l4 * 8);
        bf16x8 bv1 = *(const bf16x8*)(vT + (size_t)(dt + l15) * N_PTS + (kt + 1) * 32 + l4 * 8);
        a2b = __builtin_amdgcn_mfma_f32_16x16x32_bf16(pa1, bv1, a2b, 0, 0, 0);
    }

    // ---- normalized direct output (rows gated to l4==0 replica) ----
    if (l4 == 0) {
        #pragma unroll
        for (int r = 0; r < 4; ++r) {
            float v = (a2a[r] + a2b[r]) * rtot[r];
            out[(size_t)(bm + r) * D + dt + l15] = v;
        }
    }
}

// ------------------------------------------------------------------
extern "C" void kernel_launch(void* const* d_in, const int* in_sizes, int n_in,
                              void* d_out, int out_size, void* d_ws, size_t ws_size,
                              hipStream_t stream)
{
    const float* features = (const float*)d_in[0];  // 1024 x 128
    const float* vd       = (const float*)d_in[1];  // 1024 x 1024 x 3
    const float* W        = (const float*)d_in[2];  // 128 x 384
    const float* b        = (const float*)d_in[3];  // 384
    const float* tx       = (const float*)d_in[4];  // 3 x 400 x 128
    const float* ty       = (const float*)d_in[5];
    const float* tz       = (const float*)d_in[6];
    float* out = (float*)d_out;                     // 1024 x 128 f32

    char* w0 = (char*)d_ws;
    u16* qb       = (u16*)w0;                       // 256 KB
    u16* kb       = (u16*)(w0 + 0x40000);           // 256 KB
    u16* vT       = (u16*)(w0 + 0x80000);           // 256 KB (128x1024)
    u16* Tcat     = (u16*)(w0 + 0xC0000);           // 300 KB
    u16* Pb       = (u16*)(w0 + 0x110000);          // 2.4 MB (1024x1200 bf16)

    dim3 blk(256);

    // 1. qkv (+bias, q pre-scaled) + Tcat convert
    prep_kernel<<<dim3(246), blk, 0, stream>>>(
        features, W, b, tx, ty, tz, qb, kb, vT, Tcat);

    // 2. Pb GEMM
    p_gemm_kernel<<<dim3(19, 16), blk, 0, stream>>>(kb, Tcat, Pb);

    // 3. flash online: scores+bias+exp+PV+normalize -> out directly
    flash_online_kernel<<<dim3(256), dim3(512), 0, stream>>>(
        qb, kb, vT, Pb, vd, out);
}

// Round 9
// 25.480 us; speedup vs baseline: 3.8835x; 1.4400x over previous
//
#include <hip/hip_runtime.h>
#include <math.h>

#define N_PTS 1024
#define D 128
#define QL 400
#define PLD 1200            // 3*QL
#define SQRT_D_INV 0.08838834764831845f

typedef __attribute__((ext_vector_type(8))) short bf16x8;
typedef __attribute__((ext_vector_type(4))) float f32x4;
typedef unsigned short u16;

#define GLOBAL_AS __attribute__((address_space(1)))
#define LDS_AS    __attribute__((address_space(3)))

__device__ __forceinline__ u16 f2bf(float x) {
    union { float f; unsigned u; } v; v.f = x;
    unsigned r = v.u + 0x7fff + ((v.u >> 16) & 1);   // RNE
    return (u16)(r >> 16);
}
__device__ __forceinline__ float b2f(u16 h) {
    union { unsigned u; float f; } v; v.u = ((unsigned)h) << 16;
    return v.f;
}

// ------------------------------------------------------------------
// prep_kernel: blocks [0,96): qkv = features @ W + bias -> qb(1/sqrtD)/kb/vT
//              blocks [96,246): convert tables[1] -> Tcat bf16
// (R4-proven, unchanged)
// ------------------------------------------------------------------
__global__ __launch_bounds__(256) void prep_kernel(
    const float* __restrict__ features, const float* __restrict__ W,
    const float* __restrict__ bias,
    const float* __restrict__ tx, const float* __restrict__ ty,
    const float* __restrict__ tz,
    u16* __restrict__ qb, u16* __restrict__ kb, u16* __restrict__ vT,
    u16* __restrict__ Tcat)
{
    __shared__ __align__(16) u16 As[64 * 128];
    __shared__ __align__(16) u16 Bs[64 * 128];
    const int tid = threadIdx.x;
    const int bx = blockIdx.x;

    if (bx >= 96) {
        int e0 = (bx - 96) * 1024 + tid * 4;
        int n = e0 >> 7, k = e0 & 127;
        int sec = n / QL, r = n - sec * QL;
        const float* t = (sec == 0) ? tx : ((sec == 1) ? ty : tz);
        float4 v = *(const float4*)&t[QL * D + r * D + k];
        ushort4 o;
        o.x = f2bf(v.x); o.y = f2bf(v.y); o.z = f2bf(v.z); o.w = f2bf(v.w);
        *(ushort4*)&Tcat[e0] = o;
        return;
    }

    const int wave = tid >> 6, lane = tid & 63;
    const int wr = wave >> 1, wc = wave & 1;
    const int l15 = lane & 15, l4 = lane >> 4;
    const int bm = (bx / 6) * 64;
    const int bn = (bx % 6) * 64;

    #pragma unroll
    for (int r0 = 0; r0 < 4; ++r0) {
        int unit = r0 * 256 + tid;
        int row = unit >> 4, c16 = unit & 15;
        const float* ga = features + (size_t)(bm + row) * D + c16 * 8;
        float4 a0 = *(const float4*)ga;
        float4 a1 = *(const float4*)(ga + 4);
        u16 h[8] = {f2bf(a0.x), f2bf(a0.y), f2bf(a0.z), f2bf(a0.w),
                    f2bf(a1.x), f2bf(a1.y), f2bf(a1.z), f2bf(a1.w)};
        *(bf16x8*)(As + row * 128 + ((c16 ^ (row & 7)) * 8)) = *(bf16x8*)h;
    }
    #pragma unroll
    for (int r2 = 0; r2 < 8; ++r2) {
        int k = r2 * 16 + (tid >> 4);
        int nl = (tid & 15) * 4;
        float4 w4 = *(const float4*)&W[(size_t)k * 384 + bn + nl];
        float wv[4] = {w4.x, w4.y, w4.z, w4.w};
        #pragma unroll
        for (int e = 0; e < 4; ++e) {
            int n = nl + e;
            Bs[n * 128 + (((k >> 3) ^ (n & 7)) << 3) + (k & 7)] = f2bf(wv[e]);
        }
    }
    __syncthreads();

    f32x4 acc[2][2] = {};
    #pragma unroll
    for (int ks = 0; ks < 4; ++ks) {
        bf16x8 a[2], b[2];
        #pragma unroll
        for (int m = 0; m < 2; ++m) {
            int row = wr * 32 + m * 16 + l15;
            int c16 = ks * 4 + l4;
            a[m] = *(const bf16x8*)(As + row * 128 + ((c16 ^ (row & 7)) * 8));
        }
        #pragma unroll
        for (int n = 0; n < 2; ++n) {
            int row = wc * 32 + n * 16 + l15;
            int c16 = ks * 4 + l4;
            b[n] = *(const bf16x8*)(Bs + row * 128 + ((c16 ^ (row & 7)) * 8));
        }
        #pragma unroll
        for (int m = 0; m < 2; ++m)
            #pragma unroll
            for (int n = 0; n < 2; ++n)
                acc[m][n] = __builtin_amdgcn_mfma_f32_16x16x32_bf16(
                    a[m], b[n], acc[m][n], 0, 0, 0);
    }

    #pragma unroll
    for (int m = 0; m < 2; ++m)
        #pragma unroll
        for (int n = 0; n < 2; ++n)
            #pragma unroll
            for (int r = 0; r < 4; ++r) {
                int grow = bm + wr * 32 + m * 16 + l4 * 4 + r;
                int gcol = bn + wc * 32 + n * 16 + l15;
                float val = acc[m][n][r] + bias[gcol];
                int reg = gcol >> 7, lc = gcol & 127;
                if (reg == 0)      qb[grow * D + lc] = f2bf(val * SQRT_D_INV);
                else if (reg == 1) kb[grow * D + lc] = f2bf(val);
                else               vT[(size_t)lc * N_PTS + grow] = f2bf(val);
            }
}

// ------------------------------------------------------------------
// P GEMM: Pb = (kb @ Tcat^T)*1/sqrt(D), bf16. Zeroes cnt[64]
// (stream-ordered: completes before flash starts).
// ------------------------------------------------------------------
__global__ __launch_bounds__(256) void p_gemm_kernel(
    const u16* __restrict__ A,      // kb 1024x128
    const u16* __restrict__ B,      // Tcat 1200x128
    u16* __restrict__ Cb,           // Pb 1024x1200 bf16
    unsigned* __restrict__ cnt)     // [64]
{
    __shared__ __align__(16) u16 As[64 * 128];
    __shared__ __align__(16) u16 Bs[64 * 128];
    const int tid  = threadIdx.x;
    if (blockIdx.x == 0 && blockIdx.y == 0 && tid < 64) cnt[tid] = 0u;
    const int wave = tid >> 6, lane = tid & 63;
    const int wr = wave >> 1, wc = wave & 1;
    const int l15 = lane & 15, l4 = lane >> 4;
    const int bm = blockIdx.y * 64, bn = blockIdx.x * 64;

    #pragma unroll
    for (int r = 0; r < 4; ++r) {
        int unit = r * 256 + tid;
        int row  = unit >> 4;
        int c16  = unit & 15;
        int csw  = c16 ^ (row & 7);
        const u16* ga = A + (size_t)(bm + row) * D + csw * 8;
        __builtin_amdgcn_global_load_lds(
            (const GLOBAL_AS unsigned int*)ga,
            (LDS_AS unsigned int*)(As + r * 2048 + wave * 512), 16, 0, 0);
        int brow = bn + row; if (brow > PLD - 1) brow = PLD - 1;
        const u16* gb = B + (size_t)brow * D + csw * 8;
        __builtin_amdgcn_global_load_lds(
            (const GLOBAL_AS unsigned int*)gb,
            (LDS_AS unsigned int*)(Bs + r * 2048 + wave * 512), 16, 0, 0);
    }
    __syncthreads();

    f32x4 acc[2][2] = {};
    #pragma unroll
    for (int ks = 0; ks < 4; ++ks) {
        bf16x8 a[2], b[2];
        #pragma unroll
        for (int m = 0; m < 2; ++m) {
            int row = wr * 32 + m * 16 + l15;
            int c16 = ks * 4 + l4;
            a[m] = *(const bf16x8*)(As + row * 128 + ((c16 ^ (row & 7)) * 8));
        }
        #pragma unroll
        for (int n = 0; n < 2; ++n) {
            int row = wc * 32 + n * 16 + l15;
            int c16 = ks * 4 + l4;
            b[n] = *(const bf16x8*)(Bs + row * 128 + ((c16 ^ (row & 7)) * 8));
        }
        #pragma unroll
        for (int m = 0; m < 2; ++m)
            #pragma unroll
            for (int n = 0; n < 2; ++n)
                acc[m][n] = __builtin_amdgcn_mfma_f32_16x16x32_bf16(
                    a[m], b[n], acc[m][n], 0, 0, 0);
    }

    #pragma unroll
    for (int m = 0; m < 2; ++m)
        #pragma unroll
        for (int n = 0; n < 2; ++n)
            #pragma unroll
            for (int r = 0; r < 4; ++r) {
                int grow = bm + wr * 32 + m * 16 + l4 * 4 + r;
                int gcol = bn + wc * 32 + n * 16 + l15;
                if (gcol < PLD)
                    Cb[(size_t)grow * PLD + gcol] = f2bf(acc[m][n][r] * SQRT_D_INV);
            }
}

// ------------------------------------------------------------------
// flash_kernel: grid (64 i-tiles, 8 j-chunks). Linear block id = x+64y
// -> XCD = x%8: all 8 chunks of i-tile x share XCD x%8's L2, so the
// last-arriver reduce needs NO agent fences (same-L2 visibility;
// __syncthreads drains stores to L2 via compiler vmcnt(0)).
// ------------------------------------------------------------------
__global__ __launch_bounds__(256) void flash_kernel(
    const u16* __restrict__ qb,   // 1024x128 (pre-scaled)
    const u16* __restrict__ kb,   // 1024x128
    const u16* __restrict__ vT,   // 128x1024
    const u16* __restrict__ Pb,   // 1024x1200 bf16 (pre-scaled)
    const float* __restrict__ vd, // 1024x1024x3
    float* __restrict__ part,     // [64][8][16][128]
    float* __restrict__ rowsumC,  // [64][8][16]
    unsigned* __restrict__ cnt,   // [64]
    float* __restrict__ out)      // [1024][128]
{
    __shared__ __align__(16) u16 Pl[2432 * 8];   // 16x1200 + pad
    __shared__ __align__(16) u16 Ps[16 * 128];
    __shared__ float rsw[4][16];
    __shared__ int lastflag;
    const int tid = threadIdx.x;
    const int wave = tid >> 6, lane = tid & 63;
    const int l15 = lane & 15, l4 = lane >> 4;
    const int it = blockIdx.x;          // i tile 0..63
    const int chunk = blockIdx.y;       // 0..7
    const int bm = it * 16;
    const int bn = chunk * 128;

    // ---- stage P slab ----
    const u16* Pg = Pb + (size_t)bm * PLD;
    #pragma unroll
    for (int r0 = 0; r0 < 9; ++r0) {
        int unit = r0 * 256 + tid;
        __builtin_amdgcn_global_load_lds(
            (const GLOBAL_AS unsigned int*)(Pg + unit * 8),
            (LDS_AS unsigned int*)(Pl + r0 * 2048 + wave * 512), 16, 0, 0);
    }
    if (wave < 2) {
        int unit = 9 * 256 + tid;
        int cu = unit > 2399 ? 2399 : unit;
        __builtin_amdgcn_global_load_lds(
            (const GLOBAL_AS unsigned int*)(Pg + cu * 8),
            (LDS_AS unsigned int*)(Pl + 9 * 2048 + wave * 512), 16, 0, 0);
    }

    // ---- early vd loads ----
    float vx[2][4], vy[2][4], vz[2][4];
    #pragma unroll
    for (int nn = 0; nn < 2; ++nn)
        #pragma unroll
        for (int r = 0; r < 4; ++r) {
            int i = l4 * 4 + r;
            int j = wave * 32 + nn * 16 + l15;
            const float* vp = vd + ((size_t)(bm + i) * N_PTS + bn + j) * 3;
            vx[nn][r] = vp[0]; vy[nn][r] = vp[1]; vz[nn][r] = vp[2];
        }

    // ---- QK^T ----
    bf16x8 aq[4];
    #pragma unroll
    for (int ks = 0; ks < 4; ++ks)
        aq[ks] = *(const bf16x8*)(qb + (size_t)(bm + l15) * D + ks * 32 + l4 * 8);
    f32x4 acc[2] = {};
    #pragma unroll
    for (int nn = 0; nn < 2; ++nn) {
        int jt = bn + wave * 32 + nn * 16;
        #pragma unroll
        for (int ks = 0; ks < 4; ++ks) {
            bf16x8 bk = *(const bf16x8*)(kb + (size_t)(jt + l15) * D + ks * 32 + l4 * 8);
            acc[nn] = __builtin_amdgcn_mfma_f32_16x16x32_bf16(aq[ks], bk, acc[nn], 0, 0, 0);
        }
    }
    __syncthreads();   // Pl staged

    // ---- bias gather + exp + Ps + rowsum ----
    float rs[4] = {0.f, 0.f, 0.f, 0.f};
    #pragma unroll
    for (int nn = 0; nn < 2; ++nn)
        #pragma unroll
        for (int r = 0; r < 4; ++r) {
            int i = l4 * 4 + r;
            int jl = wave * 32 + nn * 16 + l15;
            int ix = (int)floorf((vx[nn][r] + 4.0f) * 50.0f);
            int iy = (int)floorf((vy[nn][r] + 4.0f) * 50.0f);
            int iz = (int)floorf((vz[nn][r] + 4.0f) * 50.0f);
            ix = min(max(ix, 0), QL - 1);
            iy = min(max(iy, 0), QL - 1);
            iz = min(max(iz, 0), QL - 1);
            const u16* Pr = Pl + i * PLD;
            float bv = b2f(Pr[ix]) + b2f(Pr[QL + iy]) + b2f(Pr[2 * QL + iz]);
            float e = __expf(acc[nn][r] + bv);
            rs[r] += e;
            Ps[i * 128 + (((jl >> 3) ^ (i & 7)) * 8) + (jl & 7)] = f2bf(e);
        }
    #pragma unroll
    for (int r = 0; r < 4; ++r)
        #pragma unroll
        for (int off = 1; off < 16; off <<= 1)
            rs[r] += __shfl_xor(rs[r], off);
    if (l15 == 0)
        #pragma unroll
        for (int r = 0; r < 4; ++r) rsw[wave][l4 * 4 + r] = rs[r];
    __syncthreads();
    if (tid < 16)
        rowsumC[(it * 8 + chunk) * 16 + tid] =
            rsw[0][tid] + rsw[1][tid] + rsw[2][tid] + rsw[3][tid];

    // ---- PV ----
    bf16x8 pa[4];
    #pragma unroll
    for (int kt = 0; kt < 4; ++kt)
        pa[kt] = *(const bf16x8*)(Ps + l15 * 128 + (((kt * 4 + l4) ^ (l15 & 7)) * 8));
    f32x4 acc2[2] = {};
    #pragma unroll
    for (int nn = 0; nn < 2; ++nn) {
        int dt = wave * 32 + nn * 16;
        #pragma unroll
        for (int kt = 0; kt < 4; ++kt) {
            bf16x8 bv8 = *(const bf16x8*)(vT + (size_t)(dt + l15) * N_PTS + bn + kt * 32 + l4 * 8);
            acc2[nn] = __builtin_amdgcn_mfma_f32_16x16x32_bf16(pa[kt], bv8, acc2[nn], 0, 0, 0);
        }
    }
    float* po = part + (size_t)(it * 8 + chunk) * (16 * D);
    #pragma unroll
    for (int nn = 0; nn < 2; ++nn)
        #pragma unroll
        for (int r = 0; r < 4; ++r)
            po[(l4 * 4 + r) * D + wave * 32 + nn * 16 + l15] = acc2[nn][r];

    // ---- fence-free last-arriver reduce (same-XCD L2 visibility) ----
    asm volatile("s_waitcnt vmcnt(0)" ::: "memory");  // each wave drains its stores
    __syncthreads();                                  // all waves drained (vmcnt0 + barrier)
    if (tid == 0) {
        unsigned old = __hip_atomic_fetch_add(
            &cnt[it], 1u, __ATOMIC_RELAXED, __HIP_MEMORY_SCOPE_AGENT);
        lastflag = (old == 7u);
    }
    __syncthreads();
    if (lastflag) {
        const float4* p4 = (const float4*)(part + (size_t)it * 8 * 16 * D);
        const float* rsb = rowsumC + it * 8 * 16;
        #pragma unroll
        for (int h = 0; h < 2; ++h) {
            int f4 = h * 256 + tid;            // 0..511 (16 rows x 32 f4)
            int row = f4 >> 5;
            float rsum = 0.0f;
            #pragma unroll
            for (int z = 0; z < 8; ++z) rsum += rsb[z * 16 + row];
            float inv = 1.0f / rsum;
            float4 a = p4[f4];
            #pragma unroll
            for (int z = 1; z < 8; ++z) {
                float4 v = p4[z * 512 + f4];
                a.x += v.x; a.y += v.y; a.z += v.z; a.w += v.w;
            }
            a.x *= inv; a.y *= inv; a.z *= inv; a.w *= inv;
            ((float4*)out)[bm * 32 + f4] = a;
        }
    }
}

// ------------------------------------------------------------------
extern "C" void kernel_launch(void* const* d_in, const int* in_sizes, int n_in,
                              void* d_out, int out_size, void* d_ws, size_t ws_size,
                              hipStream_t stream)
{
    const float* features = (const float*)d_in[0];  // 1024 x 128
    const float* vd       = (const float*)d_in[1];  // 1024 x 1024 x 3
    const float* W        = (const float*)d_in[2];  // 128 x 384
    const float* b        = (const float*)d_in[3];  // 384
    const float* tx       = (const float*)d_in[4];  // 3 x 400 x 128
    const float* ty       = (const float*)d_in[5];
    const float* tz       = (const float*)d_in[6];
    float* out = (float*)d_out;                     // 1024 x 128 f32

    char* w0 = (char*)d_ws;
    unsigned* cnt = (unsigned*)w0;                  // 256 B  [64]
    u16* qb       = (u16*)(w0 + 0x1000);            // 256 KB
    u16* kb       = (u16*)(w0 + 0x50000);           // 256 KB
    u16* vT       = (u16*)(w0 + 0x90000);           // 256 KB (128x1024)
    u16* Tcat     = (u16*)(w0 + 0xD0000);           // 300 KB
    u16* Pb       = (u16*)(w0 + 0x120000);          // 2.4 MB (1024x1200 bf16)
    float* part   = (float*)(w0 + 0x380000);        // 4 MB   [64][8][16][128]
    float* rowsumC= (float*)(w0 + 0x780000);        // 32 KB  [64][8][16]

    dim3 blk(256);

    // 1. qkv (+bias, q pre-scaled) + Tcat convert
    prep_kernel<<<dim3(246), blk, 0, stream>>>(
        features, W, b, tx, ty, tz, qb, kb, vT, Tcat);

    // 2. Pb GEMM (zeroes cnt, stream-ordered before flash)
    p_gemm_kernel<<<dim3(19, 16), blk, 0, stream>>>(kb, Tcat, Pb, cnt);

    // 3. flash + fence-free last-arriver reduce/normalize
    flash_kernel<<<dim3(64, 8), blk, 0, stream>>>(
        qb, kb, vT, Pb, vd, part, rowsumC, cnt, out);
}

// Round 10
// 23.848 us; speedup vs baseline: 4.1492x; 1.0684x over previous
//
#include <hip/hip_runtime.h>
#include <math.h>

#define N_PTS 1024
#define D 128
#define QL 400
#define PLD 1200            // 3*QL
#define SQRT_D_INV 0.08838834764831845f

typedef __attribute__((ext_vector_type(8))) short bf16x8;
typedef __attribute__((ext_vector_type(4))) float f32x4;
typedef unsigned short u16;

#define GLOBAL_AS __attribute__((address_space(1)))
#define LDS_AS    __attribute__((address_space(3)))

__device__ __forceinline__ u16 f2bf(float x) {
    union { float f; unsigned u; } v; v.f = x;
    unsigned r = v.u + 0x7fff + ((v.u >> 16) & 1);   // RNE
    return (u16)(r >> 16);
}
__device__ __forceinline__ float b2f(u16 h) {
    union { unsigned u; float f; } v; v.u = ((unsigned)h) << 16;
    return v.f;
}

// ------------------------------------------------------------------
// prep2_kernel: ONE dispatch, two independent roles (no cross-block deps):
//  blocks [0,96):   qkv = features@W + b -> qb(1/sqrtD)/kb/vT  (R9-proven)
//  blocks [96,400): P-role tile (ib,jb):
//      G-tile = Tcat_tile @ Wk^T (local, from raw f32 tables + W)
//      bP[c]  = b_k . Tcat[c]
//      P-tile = X_tile @ G-tile^T + bP, scaled 1/sqrt(D) -> Pb bf16
//  block 0 zeroes cnt[64] for flash's last-arriver.
// ------------------------------------------------------------------
__global__ __launch_bounds__(256) void prep2_kernel(
    const float* __restrict__ features, const float* __restrict__ W,
    const float* __restrict__ bias,
    const float* __restrict__ tx, const float* __restrict__ ty,
    const float* __restrict__ tz,
    u16* __restrict__ qb, u16* __restrict__ kb, u16* __restrict__ vT,
    u16* __restrict__ Pb, unsigned* __restrict__ cnt)
{
    __shared__ __align__(16) u16 smem[24704];   // 49.4 KB
    const int tid = threadIdx.x;
    const int bx = blockIdx.x;
    const int wave = tid >> 6, lane = tid & 63;
    const int wr = wave >> 1, wc = wave & 1;
    const int l15 = lane & 15, l4 = lane >> 4;

    if (bx == 0 && tid < 64) cnt[tid] = 0u;

    if (bx < 96) {
        // ---------------- qkv role (R9-proven) ----------------
        u16* As = smem;
        u16* Bs = smem + 8192;
        const int bm = (bx / 6) * 64;
        const int bn = (bx % 6) * 64;

        #pragma unroll
        for (int r0 = 0; r0 < 4; ++r0) {
            int unit = r0 * 256 + tid;
            int row = unit >> 4, c16 = unit & 15;
            const float* ga = features + (size_t)(bm + row) * D + c16 * 8;
            float4 a0 = *(const float4*)ga;
            float4 a1 = *(const float4*)(ga + 4);
            u16 h[8] = {f2bf(a0.x), f2bf(a0.y), f2bf(a0.z), f2bf(a0.w),
                        f2bf(a1.x), f2bf(a1.y), f2bf(a1.z), f2bf(a1.w)};
            *(bf16x8*)(As + row * 128 + ((c16 ^ (row & 7)) * 8)) = *(bf16x8*)h;
        }
        #pragma unroll
        for (int r2 = 0; r2 < 8; ++r2) {
            int k = r2 * 16 + (tid >> 4);
            int nl = (tid & 15) * 4;
            float4 w4 = *(const float4*)&W[(size_t)k * 384 + bn + nl];
            float wv[4] = {w4.x, w4.y, w4.z, w4.w};
            #pragma unroll
            for (int e = 0; e < 4; ++e) {
                int n = nl + e;
                Bs[n * 128 + (((k >> 3) ^ (n & 7)) << 3) + (k & 7)] = f2bf(wv[e]);
            }
        }
        __syncthreads();

        f32x4 acc[2][2] = {};
        #pragma unroll
        for (int ks = 0; ks < 4; ++ks) {
            bf16x8 a[2], b[2];
            #pragma unroll
            for (int m = 0; m < 2; ++m) {
                int row = wr * 32 + m * 16 + l15;
                int c16 = ks * 4 + l4;
                a[m] = *(const bf16x8*)(As + row * 128 + ((c16 ^ (row & 7)) * 8));
            }
            #pragma unroll
            for (int n = 0; n < 2; ++n) {
                int row = wc * 32 + n * 16 + l15;
                int c16 = ks * 4 + l4;
                b[n] = *(const bf16x8*)(Bs + row * 128 + ((c16 ^ (row & 7)) * 8));
            }
            #pragma unroll
            for (int m = 0; m < 2; ++m)
                #pragma unroll
                for (int n = 0; n < 2; ++n)
                    acc[m][n] = __builtin_amdgcn_mfma_f32_16x16x32_bf16(
                        a[m], b[n], acc[m][n], 0, 0, 0);
        }

        #pragma unroll
        for (int m = 0; m < 2; ++m)
            #pragma unroll
            for (int n = 0; n < 2; ++n)
                #pragma unroll
                for (int r = 0; r < 4; ++r) {
                    int grow = bm + wr * 32 + m * 16 + l4 * 4 + r;
                    int gcol = bn + wc * 32 + n * 16 + l15;
                    float val = acc[m][n][r] + bias[gcol];
                    int reg = gcol >> 7, lc = gcol & 127;
                    if (reg == 0)      qb[grow * D + lc] = f2bf(val * SQRT_D_INV);
                    else if (reg == 1) kb[grow * D + lc] = f2bf(val);
                    else               vT[(size_t)lc * N_PTS + grow] = f2bf(val);
                }
        return;
    }

    // ---------------- P role ----------------
    const int t = bx - 96;
    const int ib = t / 19, jb = t % 19;
    const int bm = ib * 64, bn = jb * 64;
    u16* Ta = smem;                         // Tcat tile 64x128; later X tile
    u16* Wb = smem + 8192;                  // Wk 128x128; later G 64x128
    float* bPl = (float*)(smem + 24576);    // 64 f32

    // stage Tcat tile (f32 tables -> bf16, swizzled)
    #pragma unroll
    for (int r0 = 0; r0 < 4; ++r0) {
        int unit = r0 * 256 + tid;
        int row = unit >> 4, c16 = unit & 15;
        int c = bn + row; if (c > PLD - 1) c = PLD - 1;
        int sec = c / QL, rr = c - sec * QL;
        const float* tsec = (sec == 0) ? tx : ((sec == 1) ? ty : tz);
        const float* ga = tsec + QL * D + rr * D + c16 * 8;
        float4 a0 = *(const float4*)ga;
        float4 a1 = *(const float4*)(ga + 4);
        u16 h[8] = {f2bf(a0.x), f2bf(a0.y), f2bf(a0.z), f2bf(a0.w),
                    f2bf(a1.x), f2bf(a1.y), f2bf(a1.z), f2bf(a1.w)};
        *(bf16x8*)(Ta + row * 128 + ((c16 ^ (row & 7)) * 8)) = *(bf16x8*)h;
    }
    // stage Wk: Wk[e][d] = W[e*384 + 128 + d], 128x128 f32 -> bf16
    #pragma unroll
    for (int r0 = 0; r0 < 8; ++r0) {
        int unit = r0 * 256 + tid;
        int e = unit >> 4, c16 = unit & 15;
        const float* ga = W + (size_t)e * 384 + 128 + c16 * 8;
        float4 a0 = *(const float4*)ga;
        float4 a1 = *(const float4*)(ga + 4);
        u16 h[8] = {f2bf(a0.x), f2bf(a0.y), f2bf(a0.z), f2bf(a0.w),
                    f2bf(a1.x), f2bf(a1.y), f2bf(a1.z), f2bf(a1.w)};
        *(bf16x8*)(Wb + e * 128 + ((c16 ^ (e & 7)) * 8)) = *(bf16x8*)h;
    }
    __syncthreads();

    // G-GEMM: G[c,e] (64x128), K = 128 (d). Per wave 32(c) x 64(e).
    f32x4 accG[2][4] = {};
    #pragma unroll
    for (int ks = 0; ks < 4; ++ks) {
        bf16x8 a[2], bfr[4];
        #pragma unroll
        for (int m = 0; m < 2; ++m) {
            int row = wr * 32 + m * 16 + l15;
            int c16 = ks * 4 + l4;
            a[m] = *(const bf16x8*)(Ta + row * 128 + ((c16 ^ (row & 7)) * 8));
        }
        #pragma unroll
        for (int n = 0; n < 4; ++n) {
            int e = wc * 64 + n * 16 + l15;
            int c16 = ks * 4 + l4;
            bfr[n] = *(const bf16x8*)(Wb + e * 128 + ((c16 ^ (e & 7)) * 8));
        }
        #pragma unroll
        for (int m = 0; m < 2; ++m)
            #pragma unroll
            for (int n = 0; n < 4; ++n)
                accG[m][n] = __builtin_amdgcn_mfma_f32_16x16x32_bf16(
                    a[m], bfr[n], accG[m][n], 0, 0, 0);
    }

    // bP[c] = sum_d b[128+d] * Tcat[c,d]  (4 lanes per c-row)
    float bsum = 0.0f;
    {
        int c_l = tid >> 2, q = tid & 3;
        #pragma unroll
        for (int dd = 0; dd < 32; ++dd) {
            int d = q * 32 + dd;
            u16 tv = Ta[c_l * 128 + (((d >> 3) ^ (c_l & 7)) * 8) + (d & 7)];
            bsum += b2f(tv) * bias[128 + d];
        }
        bsum += __shfl_xor(bsum, 1);
        bsum += __shfl_xor(bsum, 2);
    }
    __syncthreads();   // all reads of Ta/Wb complete

    // write G -> Wb (swizzled bf16); stage X tile -> Ta; write bP
    #pragma unroll
    for (int m = 0; m < 2; ++m)
        #pragma unroll
        for (int n = 0; n < 4; ++n)
            #pragma unroll
            for (int rr = 0; rr < 4; ++rr) {
                int c_l = wr * 32 + m * 16 + l4 * 4 + rr;
                int e   = wc * 64 + n * 16 + l15;
                Wb[c_l * 128 + (((e >> 3) ^ (c_l & 7)) * 8) + (e & 7)] =
                    f2bf(accG[m][n][rr]);
            }
    #pragma unroll
    for (int r0 = 0; r0 < 4; ++r0) {
        int unit = r0 * 256 + tid;
        int row = unit >> 4, c16 = unit & 15;
        const float* ga = features + (size_t)(bm + row) * D + c16 * 8;
        float4 a0 = *(const float4*)ga;
        float4 a1 = *(const float4*)(ga + 4);
        u16 h[8] = {f2bf(a0.x), f2bf(a0.y), f2bf(a0.z), f2bf(a0.w),
                    f2bf(a1.x), f2bf(a1.y), f2bf(a1.z), f2bf(a1.w)};
        *(bf16x8*)(Ta + row * 128 + ((c16 ^ (row & 7)) * 8)) = *(bf16x8*)h;
    }
    if ((tid & 3) == 0) bPl[tid >> 2] = bsum;
    __syncthreads();

    // P-GEMM: P[i,c] (64x64), K = 128 (e)
    f32x4 acc[2][2] = {};
    #pragma unroll
    for (int ks = 0; ks < 4; ++ks) {
        bf16x8 a[2], bq[2];
        #pragma unroll
        for (int m = 0; m < 2; ++m) {
            int row = wr * 32 + m * 16 + l15;
            int c16 = ks * 4 + l4;
            a[m] = *(const bf16x8*)(Ta + row * 128 + ((c16 ^ (row & 7)) * 8));
        }
        #pragma unroll
        for (int n = 0; n < 2; ++n) {
            int crow = wc * 32 + n * 16 + l15;
            int c16 = ks * 4 + l4;
            bq[n] = *(const bf16x8*)(Wb + crow * 128 + ((c16 ^ (crow & 7)) * 8));
        }
        #pragma unroll
        for (int m = 0; m < 2; ++m)
            #pragma unroll
            for (int n = 0; n < 2; ++n)
                acc[m][n] = __builtin_amdgcn_mfma_f32_16x16x32_bf16(
                    a[m], bq[n], acc[m][n], 0, 0, 0);
    }
    #pragma unroll
    for (int m = 0; m < 2; ++m)
        #pragma unroll
        for (int n = 0; n < 2; ++n)
            #pragma unroll
            for (int rr = 0; rr < 4; ++rr) {
                int grow = bm + wr * 32 + m * 16 + l4 * 4 + rr;
                int gcol = bn + wc * 32 + n * 16 + l15;
                int c_l  = wc * 32 + n * 16 + l15;
                if (gcol < PLD)
                    Pb[(size_t)grow * PLD + gcol] =
                        f2bf((acc[m][n][rr] + bPl[c_l]) * SQRT_D_INV);
            }
}

// ------------------------------------------------------------------
// flash_kernel (R9-proven, unchanged): grid (64 i-tiles, 8 j-chunks);
// fence-free last-arriver reduce via same-XCD L2 visibility.
// ------------------------------------------------------------------
__global__ __launch_bounds__(256) void flash_kernel(
    const u16* __restrict__ qb,   // 1024x128 (pre-scaled)
    const u16* __restrict__ kb,   // 1024x128
    const u16* __restrict__ vT,   // 128x1024
    const u16* __restrict__ Pb,   // 1024x1200 bf16 (pre-scaled)
    const float* __restrict__ vd, // 1024x1024x3
    float* __restrict__ part,     // [64][8][16][128]
    float* __restrict__ rowsumC,  // [64][8][16]
    unsigned* __restrict__ cnt,   // [64]
    float* __restrict__ out)      // [1024][128]
{
    __shared__ __align__(16) u16 Pl[2432 * 8];   // 16x1200 + pad
    __shared__ __align__(16) u16 Ps[16 * 128];
    __shared__ float rsw[4][16];
    __shared__ int lastflag;
    const int tid = threadIdx.x;
    const int wave = tid >> 6, lane = tid & 63;
    const int l15 = lane & 15, l4 = lane >> 4;
    const int it = blockIdx.x;          // i tile 0..63
    const int chunk = blockIdx.y;       // 0..7
    const int bm = it * 16;
    const int bn = chunk * 128;

    // ---- stage P slab ----
    const u16* Pg = Pb + (size_t)bm * PLD;
    #pragma unroll
    for (int r0 = 0; r0 < 9; ++r0) {
        int unit = r0 * 256 + tid;
        __builtin_amdgcn_global_load_lds(
            (const GLOBAL_AS unsigned int*)(Pg + unit * 8),
            (LDS_AS unsigned int*)(Pl + r0 * 2048 + wave * 512), 16, 0, 0);
    }
    if (wave < 2) {
        int unit = 9 * 256 + tid;
        int cu = unit > 2399 ? 2399 : unit;
        __builtin_amdgcn_global_load_lds(
            (const GLOBAL_AS unsigned int*)(Pg + cu * 8),
            (LDS_AS unsigned int*)(Pl + 9 * 2048 + wave * 512), 16, 0, 0);
    }

    // ---- early vd loads ----
    float vx[2][4], vy[2][4], vz[2][4];
    #pragma unroll
    for (int nn = 0; nn < 2; ++nn)
        #pragma unroll
        for (int r = 0; r < 4; ++r) {
            int i = l4 * 4 + r;
            int j = wave * 32 + nn * 16 + l15;
            const float* vp = vd + ((size_t)(bm + i) * N_PTS + bn + j) * 3;
            vx[nn][r] = vp[0]; vy[nn][r] = vp[1]; vz[nn][r] = vp[2];
        }

    // ---- QK^T ----
    bf16x8 aq[4];
    #pragma unroll
    for (int ks = 0; ks < 4; ++ks)
        aq[ks] = *(const bf16x8*)(qb + (size_t)(bm + l15) * D + ks * 32 + l4 * 8);
    f32x4 acc[2] = {};
    #pragma unroll
    for (int nn = 0; nn < 2; ++nn) {
        int jt = bn + wave * 32 + nn * 16;
        #pragma unroll
        for (int ks = 0; ks < 4; ++ks) {
            bf16x8 bk = *(const bf16x8*)(kb + (size_t)(jt + l15) * D + ks * 32 + l4 * 8);
            acc[nn] = __builtin_amdgcn_mfma_f32_16x16x32_bf16(aq[ks], bk, acc[nn], 0, 0, 0);
        }
    }
    __syncthreads();   // Pl staged

    // ---- bias gather + exp + Ps + rowsum ----
    float rs[4] = {0.f, 0.f, 0.f, 0.f};
    #pragma unroll
    for (int nn = 0; nn < 2; ++nn)
        #pragma unroll
        for (int r = 0; r < 4; ++r) {
            int i = l4 * 4 + r;
            int jl = wave * 32 + nn * 16 + l15;
            int ix = (int)floorf((vx[nn][r] + 4.0f) * 50.0f);
            int iy = (int)floorf((vy[nn][r] + 4.0f) * 50.0f);
            int iz = (int)floorf((vz[nn][r] + 4.0f) * 50.0f);
            ix = min(max(ix, 0), QL - 1);
            iy = min(max(iy, 0), QL - 1);
            iz = min(max(iz, 0), QL - 1);
            const u16* Pr = Pl + i * PLD;
            float bv = b2f(Pr[ix]) + b2f(Pr[QL + iy]) + b2f(Pr[2 * QL + iz]);
            float e = __expf(acc[nn][r] + bv);
            rs[r] += e;
            Ps[i * 128 + (((jl >> 3) ^ (i & 7)) * 8) + (jl & 7)] = f2bf(e);
        }
    #pragma unroll
    for (int r = 0; r < 4; ++r)
        #pragma unroll
        for (int off = 1; off < 16; off <<= 1)
            rs[r] += __shfl_xor(rs[r], off);
    if (l15 == 0)
        #pragma unroll
        for (int r = 0; r < 4; ++r) rsw[wave][l4 * 4 + r] = rs[r];
    __syncthreads();
    if (tid < 16)
        rowsumC[(it * 8 + chunk) * 16 + tid] =
            rsw[0][tid] + rsw[1][tid] + rsw[2][tid] + rsw[3][tid];

    // ---- PV ----
    bf16x8 pa[4];
    #pragma unroll
    for (int kt = 0; kt < 4; ++kt)
        pa[kt] = *(const bf16x8*)(Ps + l15 * 128 + (((kt * 4 + l4) ^ (l15 & 7)) * 8));
    f32x4 acc2[2] = {};
    #pragma unroll
    for (int nn = 0; nn < 2; ++nn) {
        int dt = wave * 32 + nn * 16;
        #pragma unroll
        for (int kt = 0; kt < 4; ++kt) {
            bf16x8 bv8 = *(const bf16x8*)(vT + (size_t)(dt + l15) * N_PTS + bn + kt * 32 + l4 * 8);
            acc2[nn] = __builtin_amdgcn_mfma_f32_16x16x32_bf16(pa[kt], bv8, acc2[nn], 0, 0, 0);
        }
    }
    float* po = part + (size_t)(it * 8 + chunk) * (16 * D);
    #pragma unroll
    for (int nn = 0; nn < 2; ++nn)
        #pragma unroll
        for (int r = 0; r < 4; ++r)
            po[(l4 * 4 + r) * D + wave * 32 + nn * 16 + l15] = acc2[nn][r];

    // ---- fence-free last-arriver reduce (same-XCD L2 visibility) ----
    asm volatile("s_waitcnt vmcnt(0)" ::: "memory");  // each wave drains its stores
    __syncthreads();                                  // all waves drained
    if (tid == 0) {
        unsigned old = __hip_atomic_fetch_add(
            &cnt[it], 1u, __ATOMIC_RELAXED, __HIP_MEMORY_SCOPE_AGENT);
        lastflag = (old == 7u);
    }
    __syncthreads();
    if (lastflag) {
        const float4* p4 = (const float4*)(part + (size_t)it * 8 * 16 * D);
        const float* rsb = rowsumC + it * 8 * 16;
        #pragma unroll
        for (int h = 0; h < 2; ++h) {
            int f4 = h * 256 + tid;            // 0..511 (16 rows x 32 f4)
            int row = f4 >> 5;
            float rsum = 0.0f;
            #pragma unroll
            for (int z = 0; z < 8; ++z) rsum += rsb[z * 16 + row];
            float inv = 1.0f / rsum;
            float4 a = p4[f4];
            #pragma unroll
            for (int z = 1; z < 8; ++z) {
                float4 v = p4[z * 512 + f4];
                a.x += v.x; a.y += v.y; a.z += v.z; a.w += v.w;
            }
            a.x *= inv; a.y *= inv; a.z *= inv; a.w *= inv;
            ((float4*)out)[bm * 32 + f4] = a;
        }
    }
}

// ------------------------------------------------------------------
extern "C" void kernel_launch(void* const* d_in, const int* in_sizes, int n_in,
                              void* d_out, int out_size, void* d_ws, size_t ws_size,
                              hipStream_t stream)
{
    const float* features = (const float*)d_in[0];  // 1024 x 128
    const float* vd       = (const float*)d_in[1];  // 1024 x 1024 x 3
    const float* W        = (const float*)d_in[2];  // 128 x 384
    const float* b        = (const float*)d_in[3];  // 384
    const float* tx       = (const float*)d_in[4];  // 3 x 400 x 128
    const float* ty       = (const float*)d_in[5];
    const float* tz       = (const float*)d_in[6];
    float* out = (float*)d_out;                     // 1024 x 128 f32

    char* w0 = (char*)d_ws;
    unsigned* cnt = (unsigned*)w0;                  // 256 B  [64]
    u16* qb       = (u16*)(w0 + 0x1000);            // 256 KB
    u16* kb       = (u16*)(w0 + 0x50000);           // 256 KB
    u16* vT       = (u16*)(w0 + 0x90000);           // 256 KB (128x1024)
    u16* Pb       = (u16*)(w0 + 0xD0000);           // 2.4 MB (1024x1200 bf16)
    float* part   = (float*)(w0 + 0x330000);        // 4 MB   [64][8][16][128]
    float* rowsumC= (float*)(w0 + 0x730000);        // 32 KB  [64][8][16]

    dim3 blk(256);

    // 1. qkv + P (independent roles, one dispatch; zeroes cnt)
    prep2_kernel<<<dim3(400), blk, 0, stream>>>(
        features, W, b, tx, ty, tz, qb, kb, vT, Pb, cnt);

    // 2. flash + fence-free last-arriver reduce/normalize
    flash_kernel<<<dim3(64, 8), blk, 0, stream>>>(
        qb, kb, vT, Pb, vd, part, rowsumC, cnt, out);
}